// Round 1
// baseline (221.179 us; speedup 1.0000x reference)
//
#include <hip/hip_runtime.h>

#define N_NODES 10000
#define N_EDGES 30000
#define DIN     64
#define EDIM    16
#define H1      128
#define H2      64
#define C_OUT   10

// ---------------------------------------------------------------------------
// K1: h = relu(x @ W1 + b1)   [10000,64]@[64,128]
// block 256 = 8 nodes x 32 o-groups(4)
__global__ __launch_bounds__(256) void k1_node_linear(
        const float* __restrict__ x, const float* __restrict__ W1,
        const float* __restrict__ b1, float* __restrict__ h) {
    __shared__ float w_lds[DIN * H1];   // 32 KB
    __shared__ float b_lds[H1];
    __shared__ float x_lds[8][DIN];
    int t = threadIdx.x;
    for (int idx = t; idx < DIN * H1 / 4; idx += 256)
        ((float4*)w_lds)[idx] = ((const float4*)W1)[idx];
    if (t < H1) b_lds[t] = b1[t];
    int n0 = blockIdx.x * 8;
    if (t < 128) {
        int row = t >> 4, c4 = t & 15;
        int n = n0 + row;
        float4 v = make_float4(0.f, 0.f, 0.f, 0.f);
        if (n < N_NODES) v = ((const float4*)(x + (size_t)n * DIN))[c4];
        ((float4*)(x_lds[row]))[c4] = v;
    }
    __syncthreads();
    int nl = t >> 5;
    int o  = (t & 31) * 4;
    int n  = n0 + nl;
    float4 acc = *(const float4*)&b_lds[o];
    #pragma unroll 8
    for (int i = 0; i < DIN; ++i) {
        float xv = x_lds[nl][i];
        float4 w = *(const float4*)&w_lds[i * H1 + o];
        acc.x = fmaf(xv, w.x, acc.x);
        acc.y = fmaf(xv, w.y, acc.y);
        acc.z = fmaf(xv, w.z, acc.z);
        acc.w = fmaf(xv, w.w, acc.w);
    }
    if (n < N_NODES) {
        acc.x = fmaxf(acc.x, 0.f); acc.y = fmaxf(acc.y, 0.f);
        acc.z = fmaxf(acc.z, 0.f); acc.w = fmaxf(acc.w, 0.f);
        *(float4*)&h[(size_t)n * H1 + o] = acc;
    }
}

// ---------------------------------------------------------------------------
// K3: fused node-side GEMMs, all of shape [64 nodes] x [K=128] x [N=64]:
//   grid.y = y in [0,16): G1[n, y*64+o]  = sum_i h[n,i] * We1[y*8192 + i*64 + o]
//   y == 16:              hrb1[n,o]      = sum_i h[n,i] * root1[i*64+o] + bias1[o]
//   y == 17:              hb1[n,o]       = sum_i h[n,i] * be1[i*64+o]
// block 256: tx = o-group(4), ty = node-group(4); K staged in 2 halves of 64.
__global__ __launch_bounds__(256) void k3_node_gemm(
        const float* __restrict__ h, const float* __restrict__ We1,
        const float* __restrict__ root1, const float* __restrict__ be1,
        const float* __restrict__ bias1,
        float* __restrict__ G1, float* __restrict__ hrb1, float* __restrict__ hb1) {
    __shared__ float a_lds[64][H1 + 4];   // stride 132: 16B-aligned rows, 2-way max
    __shared__ float b_lds[64 * 64];      // one K-half of B: 16 KB
    int t = threadIdx.x;
    int y = blockIdx.y;
    const float* Bsrc = (y < 16) ? (We1 + (size_t)y * (H1 * H2))
                                 : (y == 16 ? root1 : be1);
    int n0 = blockIdx.x * 64;
    // stage A: 64 rows x 128 floats (2048 float4)
    for (int idx = t; idx < 2048; idx += 256) {
        int row = idx >> 5, c4 = idx & 31;
        int n = n0 + row;
        float4 v = make_float4(0.f, 0.f, 0.f, 0.f);
        if (n < N_NODES) v = ((const float4*)(h + (size_t)n * H1))[c4];
        *(float4*)&a_lds[row][c4 * 4] = v;
    }
    int tx = t & 15, ty = t >> 4;   // per-wave: tx 0..15, ty 0..3 (4 ty values)
    float acc[4][4] = {};
    for (int ks = 0; ks < 2; ++ks) {
        for (int idx = t; idx < 1024; idx += 256)
            ((float4*)b_lds)[idx] = ((const float4*)(Bsrc + ks * 64 * 64))[idx];
        __syncthreads();
        #pragma unroll 8
        for (int i = 0; i < 64; i += 2) {
            float4 b0  = *(const float4*)&b_lds[i * 64 + tx * 4];
            float4 b1v = *(const float4*)&b_lds[(i + 1) * 64 + tx * 4];
            int ig = ks * 64 + i;
            #pragma unroll
            for (int nn = 0; nn < 4; ++nn) {
                float2 av = *(const float2*)&a_lds[ty * 4 + nn][ig];
                acc[nn][0] = fmaf(av.x, b0.x,  acc[nn][0]);
                acc[nn][1] = fmaf(av.x, b0.y,  acc[nn][1]);
                acc[nn][2] = fmaf(av.x, b0.z,  acc[nn][2]);
                acc[nn][3] = fmaf(av.x, b0.w,  acc[nn][3]);
                acc[nn][0] = fmaf(av.y, b1v.x, acc[nn][0]);
                acc[nn][1] = fmaf(av.y, b1v.y, acc[nn][1]);
                acc[nn][2] = fmaf(av.y, b1v.z, acc[nn][2]);
                acc[nn][3] = fmaf(av.y, b1v.w, acc[nn][3]);
            }
        }
        __syncthreads();
    }
    int o = tx * 4;
    #pragma unroll
    for (int nn = 0; nn < 4; ++nn) {
        int n = n0 + ty * 4 + nn;
        if (n >= N_NODES) continue;
        float4 v = make_float4(acc[nn][0], acc[nn][1], acc[nn][2], acc[nn][3]);
        if (y < 16) {
            *(float4*)&G1[(size_t)n * 1024 + y * 64 + o] = v;
        } else if (y == 16) {
            v.x += bias1[o]; v.y += bias1[o + 1]; v.z += bias1[o + 2]; v.w += bias1[o + 3];
            *(float4*)&hrb1[(size_t)n * 64 + o] = v;
        } else {
            *(float4*)&hb1[(size_t)n * 64 + o] = v;
        }
    }
}

// ---------------------------------------------------------------------------
// K4: edge pass 1. wave per edge, lane = output o.
// msg[e,o] = hb1[src,o] + sum_k ea[e,k]*G1[src, k*64+o];  atomicAdd agg1[dst,o]
__global__ __launch_bounds__(256) void k4_edge1(
        const float* __restrict__ ea, const int* __restrict__ src_idx,
        const int* __restrict__ dst_idx, const float* __restrict__ G1,
        const float* __restrict__ hb1, float* __restrict__ agg1) {
    int t = threadIdx.x;
    int e = blockIdx.x * 4 + (t >> 6);
    int o = t & 63;
    if (e >= N_EDGES) return;
    int s = src_idx[e], d = dst_idx[e];
    float m = hb1[(size_t)s * 64 + o];
    const float* g = G1 + (size_t)s * 1024 + o;
    const float* a = ea + (size_t)e * 16;
    #pragma unroll
    for (int k = 0; k < 16; ++k) m = fmaf(a[k], g[k * 64], m);
    atomicAdd(&agg1[(size_t)d * 64 + o], m);
}

// ---------------------------------------------------------------------------
// K5: h2 = relu(agg1 + hrb1)
__global__ void k5_h2(const float* __restrict__ agg1, const float* __restrict__ hrb1,
                      float* __restrict__ h2) {
    int i = blockIdx.x * blockDim.x + threadIdx.x;
    if (i < N_NODES * H2) h2[i] = fmaxf(agg1[i] + hrb1[i], 0.f);
}

// ---------------------------------------------------------------------------
// K6: node-side GEMMs for layer 2. thread = (node, slot), slot in [0,18):
//   slot<16: G2[n, slot*10+c] = sum_j h2[n,j]*We2[slot*640 + j*10 + c]
//   slot16 : hb2[n,c] = sum_j h2[n,j]*be2[j*10+c]
//   slot17 : hr2[n,c] = sum_j h2[n,j]*root2[j*10+c] + bias2[c]
__global__ __launch_bounds__(256) void k6_node_gemm2(
        const float* __restrict__ h2, const float* __restrict__ We2,
        const float* __restrict__ be2, const float* __restrict__ root2,
        const float* __restrict__ bias2,
        float* __restrict__ G2, float* __restrict__ hb2, float* __restrict__ hr2) {
    __shared__ float b_all[18 * 648];   // padded stride breaks bank alignment
    int t = threadIdx.x;
    for (int idx = t; idx < 18 * 640; idx += 256) {
        int slot = idx / 640, rem = idx - slot * 640;
        float v = (slot < 16) ? We2[slot * 640 + rem]
                              : (slot == 16 ? be2[rem] : root2[rem]);
        b_all[slot * 648 + rem] = v;
    }
    __syncthreads();
    int tg = blockIdx.x * 256 + t;
    if (tg >= N_NODES * 18) return;
    int n = tg / 18, slot = tg - n * 18;
    const float* B = &b_all[slot * 648];
    const float* hrow = h2 + (size_t)n * 64;
    float acc[10] = {};
    for (int j = 0; j < 64; ++j) {
        float hv = hrow[j];
        #pragma unroll
        for (int c = 0; c < 10; ++c) acc[c] = fmaf(hv, B[j * 10 + c], acc[c]);
    }
    float* outp;
    if (slot < 16)      outp = G2 + (size_t)n * 160 + slot * 10;
    else if (slot == 16) outp = hb2 + (size_t)n * 10;
    else {
        outp = hr2 + (size_t)n * 10;
        #pragma unroll
        for (int c = 0; c < 10; ++c) acc[c] += bias2[c];
    }
    #pragma unroll
    for (int c = 0; c < 10; ++c) outp[c] = acc[c];
}

// ---------------------------------------------------------------------------
// K7: edge pass 2. thread per edge.
__global__ void k7_edge2(const float* __restrict__ ea, const int* __restrict__ src_idx,
                         const int* __restrict__ dst_idx, const float* __restrict__ G2,
                         const float* __restrict__ hb2, float* __restrict__ agg2) {
    int e = blockIdx.x * blockDim.x + threadIdx.x;
    if (e >= N_EDGES) return;
    int s = src_idx[e], d = dst_idx[e];
    float msg[10];
    #pragma unroll
    for (int c = 0; c < 10; ++c) msg[c] = hb2[(size_t)s * 10 + c];
    const float* a = ea + (size_t)e * 16;
    const float* g = G2 + (size_t)s * 160;
    #pragma unroll
    for (int k = 0; k < 16; ++k) {
        float av = a[k];
        #pragma unroll
        for (int c = 0; c < 10; ++c) msg[c] = fmaf(av, g[k * 10 + c], msg[c]);
    }
    #pragma unroll
    for (int c = 0; c < 10; ++c) atomicAdd(&agg2[(size_t)d * 10 + c], msg[c]);
}

// ---------------------------------------------------------------------------
// K8: z = agg2 + hr2; out = log_softmax(z)
__global__ void k8_logsoftmax(const float* __restrict__ agg2, const float* __restrict__ hr2,
                              float* __restrict__ out) {
    int n = blockIdx.x * blockDim.x + threadIdx.x;
    if (n >= N_NODES) return;
    float z[10]; float m = -1e30f;
    #pragma unroll
    for (int c = 0; c < 10; ++c) {
        z[c] = agg2[(size_t)n * 10 + c] + hr2[(size_t)n * 10 + c];
        m = fmaxf(m, z[c]);
    }
    float s = 0.f;
    #pragma unroll
    for (int c = 0; c < 10; ++c) s += expf(z[c] - m);
    float ls = logf(s);
    #pragma unroll
    for (int c = 0; c < 10; ++c) out[(size_t)n * 10 + c] = z[c] - m - ls;
}

// ---------------------------------------------------------------------------
extern "C" void kernel_launch(void* const* d_in, const int* in_sizes, int n_in,
                              void* d_out, int out_size, void* d_ws, size_t ws_size,
                              hipStream_t stream) {
    const float* x     = (const float*)d_in[0];
    const float* ea    = (const float*)d_in[1];
    const int*   eidx  = (const int*)d_in[2];
    const float* W1    = (const float*)d_in[3];
    const float* b1    = (const float*)d_in[4];
    const float* We1   = (const float*)d_in[5];
    const float* be1   = (const float*)d_in[6];
    const float* root1 = (const float*)d_in[7];
    const float* bias1 = (const float*)d_in[8];
    const float* We2   = (const float*)d_in[9];
    const float* be2   = (const float*)d_in[10];
    const float* root2 = (const float*)d_in[11];
    const float* bias2 = (const float*)d_in[12];
    float* out = (float*)d_out;

    float* ws   = (float*)d_ws;
    float* h    = ws;                    // 1,280,000
    float* G1   = h    + 1280000;        // 10,240,000
    float* hrb1 = G1   + 10240000;       //   640,000
    float* hb1  = hrb1 + 640000;         //   640,000
    float* agg1 = hb1  + 640000;         //   640,000
    float* h2   = agg1 + 640000;         //   640,000
    float* G2   = h2   + 640000;         // 1,600,000
    float* hb2  = G2   + 1600000;        //   100,000
    float* hr2  = hb2  + 100000;         //   100,000
    float* agg2 = hr2  + 100000;         //   100,000

    hipMemsetAsync(agg1, 0, 640000 * sizeof(float), stream);
    hipMemsetAsync(agg2, 0, 100000 * sizeof(float), stream);

    k1_node_linear<<<1250, 256, 0, stream>>>(x, W1, b1, h);
    k3_node_gemm<<<dim3(157, 18), 256, 0, stream>>>(h, We1, root1, be1, bias1,
                                                    G1, hrb1, hb1);
    k4_edge1<<<7500, 256, 0, stream>>>(ea, eidx, eidx + N_EDGES, G1, hb1, agg1);
    k5_h2<<<2500, 256, 0, stream>>>(agg1, hrb1, h2);
    k6_node_gemm2<<<704, 256, 0, stream>>>(h2, We2, be2, root2, bias2, G2, hb2, hr2);
    k7_edge2<<<118, 256, 0, stream>>>(ea, eidx, eidx + N_EDGES, G2, hb2, agg2);
    k8_logsoftmax<<<40, 256, 0, stream>>>(agg2, hr2, out);
}

// Round 2
// 186.242 us; speedup vs baseline: 1.1876x; 1.1876x over previous
//
#include <hip/hip_runtime.h>

#define N_NODES 10000
#define N_EDGES 30000
#define DIN     64
#define EDIM    16
#define H1      128
#define H2      64
#define C_OUT   10

typedef __bf16 bfrag __attribute__((ext_vector_type(8)));
typedef float  f32x4 __attribute__((ext_vector_type(4)));

__device__ __forceinline__ ushort f2bf(float f) {
    union { float f; unsigned u; } x; x.f = f;
    unsigned r = x.u + 0x7fffu + ((x.u >> 16) & 1u);   // RNE; inputs are finite
    return (ushort)(r >> 16);
}
__device__ __forceinline__ float bf2f(ushort s) {
    union { unsigned u; float f; } x; x.u = ((unsigned)s) << 16;
    return x.f;
}

// ---------------------------------------------------------------------------
// K1: h = relu(x @ W1 + b1)   [10000,64]@[64,128], output bf16
__global__ __launch_bounds__(256) void k1_node_linear(
        const float* __restrict__ x, const float* __restrict__ W1,
        const float* __restrict__ b1, ushort* __restrict__ h_bf) {
    __shared__ float w_lds[DIN * H1];   // 32 KB
    __shared__ float b_lds[H1];
    __shared__ float x_lds[8][DIN];
    int t = threadIdx.x;
    for (int idx = t; idx < DIN * H1 / 4; idx += 256)
        ((float4*)w_lds)[idx] = ((const float4*)W1)[idx];
    if (t < H1) b_lds[t] = b1[t];
    int n0 = blockIdx.x * 8;
    if (t < 128) {
        int row = t >> 4, c4 = t & 15;
        int n = n0 + row;
        float4 v = make_float4(0.f, 0.f, 0.f, 0.f);
        if (n < N_NODES) v = ((const float4*)(x + (size_t)n * DIN))[c4];
        ((float4*)(x_lds[row]))[c4] = v;
    }
    __syncthreads();
    int nl = t >> 5;
    int o  = (t & 31) * 4;
    int n  = n0 + nl;
    float4 acc = *(const float4*)&b_lds[o];
    #pragma unroll 8
    for (int i = 0; i < DIN; ++i) {
        float xv = x_lds[nl][i];
        float4 w = *(const float4*)&w_lds[i * H1 + o];
        acc.x = fmaf(xv, w.x, acc.x);
        acc.y = fmaf(xv, w.y, acc.y);
        acc.z = fmaf(xv, w.z, acc.z);
        acc.w = fmaf(xv, w.w, acc.w);
    }
    if (n < N_NODES) {
        ushort4 s;
        s.x = f2bf(fmaxf(acc.x, 0.f));
        s.y = f2bf(fmaxf(acc.y, 0.f));
        s.z = f2bf(fmaxf(acc.z, 0.f));
        s.w = f2bf(fmaxf(acc.w, 0.f));
        *(ushort4*)&h_bf[(size_t)n * H1 + o] = s;
    }
}

// ---------------------------------------------------------------------------
// K2: pack B into k-major bf16: Bt[c][i], c in [0,1152).
//   c<1024: col (y= c>>6, o = c&63) of We1[y*8192 + i*64 + o]
//   c in [1024,1088): root1[i*64 + (c-1024)]
//   c in [1088,1152): be1[i*64 + (c-1088)]
__global__ void k2_prep(const float* __restrict__ We1, const float* __restrict__ root1,
                        const float* __restrict__ be1, ushort* __restrict__ Bt) {
    int idx = blockIdx.x * 256 + threadIdx.x;   // = c*128 + i
    if (idx >= 1152 * 128) return;
    int c = idx >> 7, i = idx & 127;
    float v;
    if (c < 1024)      v = We1[(size_t)(c >> 6) * (H1 * H2) + i * 64 + (c & 63)];
    else if (c < 1088) v = root1[i * 64 + (c - 1024)];
    else               v = be1[i * 64 + (c - 1088)];
    Bt[idx] = f2bf(v);
}

// ---------------------------------------------------------------------------
// K3: bf16 MFMA GEMM  C[10000 x 1152] = h_bf[10000 x 128] @ B[128 x 1152]
// grid.x = M-tiles of 64 (157), grid.y = col-blocks of 64 (18).
//   y<16 -> G1 (bf16), y==16 -> hrb1 = .+bias1 (f32), y==17 -> hb1 (f32)
// block 256 = 4 waves; wave computes 16 rows x 64 cols via 4 col-tiles.
// Fragments loaded straight from global (A/B tiles tiny & cache-resident).
__global__ __launch_bounds__(256) void k3_mfma(
        const ushort* __restrict__ h_bf, const ushort* __restrict__ Bt,
        const float* __restrict__ bias1,
        ushort* __restrict__ G1, float* __restrict__ hrb1, float* __restrict__ hb1) {
    int t = threadIdx.x;
    int wave = t >> 6, lane = t & 63;
    int quad = lane >> 4, lrow = lane & 15;
    int y = blockIdx.y;
    int n0 = blockIdx.x * 64 + wave * 16;
    int arow = n0 + lrow; if (arow >= N_NODES) arow = N_NODES - 1;  // clamp, guarded on store
    const ushort* bbase = Bt + (size_t)y * 64 * 128;
    f32x4 acc[4] = {};
    #pragma unroll
    for (int kc = 0; kc < 128; kc += 32) {
        bfrag a = *reinterpret_cast<const bfrag*>(h_bf + (size_t)arow * 128 + kc + quad * 8);
        #pragma unroll
        for (int ct = 0; ct < 4; ++ct) {
            bfrag b = *reinterpret_cast<const bfrag*>(
                bbase + (size_t)(ct * 16 + lrow) * 128 + kc + quad * 8);
            acc[ct] = __builtin_amdgcn_mfma_f32_16x16x32_bf16(a, b, acc[ct], 0, 0, 0);
        }
    }
    // C/D layout: col = lane&15, row = quad*4 + r   [verified m89/m91]
    #pragma unroll
    for (int ct = 0; ct < 4; ++ct) {
        int col = ct * 16 + lrow;
        #pragma unroll
        for (int r = 0; r < 4; ++r) {
            int n = n0 + quad * 4 + r;
            if (n >= N_NODES) continue;
            float v = acc[ct][r];
            if (y < 16) {
                G1[(size_t)n * 1024 + y * 64 + col] = f2bf(v);
            } else if (y == 16) {
                hrb1[(size_t)n * 64 + col] = v + bias1[col];
            } else {
                hb1[(size_t)n * 64 + col] = v;
            }
        }
    }
}

// ---------------------------------------------------------------------------
// K4: edge pass 1. wave per edge, lane = output o. G1 in bf16.
__global__ __launch_bounds__(256) void k4_edge1(
        const float* __restrict__ ea, const int* __restrict__ src_idx,
        const int* __restrict__ dst_idx, const ushort* __restrict__ G1,
        const float* __restrict__ hb1, float* __restrict__ agg1) {
    int t = threadIdx.x;
    int e = blockIdx.x * 4 + (t >> 6);
    int o = t & 63;
    if (e >= N_EDGES) return;
    int s = src_idx[e], d = dst_idx[e];
    float m = hb1[(size_t)s * 64 + o];
    const ushort* g = G1 + (size_t)s * 1024 + o;
    const float* a = ea + (size_t)e * 16;
    #pragma unroll
    for (int k = 0; k < 16; ++k) m = fmaf(a[k], bf2f(g[k * 64]), m);
    atomicAdd(&agg1[(size_t)d * 64 + o], m);
}

// ---------------------------------------------------------------------------
// K5: h2 = relu(agg1 + hrb1)
__global__ void k5_h2(const float* __restrict__ agg1, const float* __restrict__ hrb1,
                      float* __restrict__ h2) {
    int i = blockIdx.x * blockDim.x + threadIdx.x;
    if (i < N_NODES * H2) h2[i] = fmaxf(agg1[i] + hrb1[i], 0.f);
}

// ---------------------------------------------------------------------------
// K6: node-side GEMMs for layer 2 (fp32, small).
__global__ __launch_bounds__(256) void k6_node_gemm2(
        const float* __restrict__ h2, const float* __restrict__ We2,
        const float* __restrict__ be2, const float* __restrict__ root2,
        const float* __restrict__ bias2,
        float* __restrict__ G2, float* __restrict__ hb2, float* __restrict__ hr2) {
    __shared__ float b_all[18 * 648];
    int t = threadIdx.x;
    for (int idx = t; idx < 18 * 640; idx += 256) {
        int slot = idx / 640, rem = idx - slot * 640;
        float v = (slot < 16) ? We2[slot * 640 + rem]
                              : (slot == 16 ? be2[rem] : root2[rem]);
        b_all[slot * 648 + rem] = v;
    }
    __syncthreads();
    int tg = blockIdx.x * 256 + t;
    if (tg >= N_NODES * 18) return;
    int n = tg / 18, slot = tg - n * 18;
    const float* B = &b_all[slot * 648];
    const float* hrow = h2 + (size_t)n * 64;
    float acc[10] = {};
    for (int j = 0; j < 64; ++j) {
        float hv = hrow[j];
        #pragma unroll
        for (int c = 0; c < 10; ++c) acc[c] = fmaf(hv, B[j * 10 + c], acc[c]);
    }
    float* outp;
    if (slot < 16)       outp = G2 + (size_t)n * 160 + slot * 10;
    else if (slot == 16) outp = hb2 + (size_t)n * 10;
    else {
        outp = hr2 + (size_t)n * 10;
        #pragma unroll
        for (int c = 0; c < 10; ++c) acc[c] += bias2[c];
    }
    #pragma unroll
    for (int c = 0; c < 10; ++c) outp[c] = acc[c];
}

// ---------------------------------------------------------------------------
// K7: edge pass 2. thread per edge.
__global__ void k7_edge2(const float* __restrict__ ea, const int* __restrict__ src_idx,
                         const int* __restrict__ dst_idx, const float* __restrict__ G2,
                         const float* __restrict__ hb2, float* __restrict__ agg2) {
    int e = blockIdx.x * blockDim.x + threadIdx.x;
    if (e >= N_EDGES) return;
    int s = src_idx[e], d = dst_idx[e];
    float msg[10];
    #pragma unroll
    for (int c = 0; c < 10; ++c) msg[c] = hb2[(size_t)s * 10 + c];
    const float* a = ea + (size_t)e * 16;
    const float* g = G2 + (size_t)s * 160;
    #pragma unroll
    for (int k = 0; k < 16; ++k) {
        float av = a[k];
        #pragma unroll
        for (int c = 0; c < 10; ++c) msg[c] = fmaf(av, g[k * 10 + c], msg[c]);
    }
    #pragma unroll
    for (int c = 0; c < 10; ++c) atomicAdd(&agg2[(size_t)d * 10 + c], msg[c]);
}

// ---------------------------------------------------------------------------
// K8: z = agg2 + hr2; out = log_softmax(z)
__global__ void k8_logsoftmax(const float* __restrict__ agg2, const float* __restrict__ hr2,
                              float* __restrict__ out) {
    int n = blockIdx.x * blockDim.x + threadIdx.x;
    if (n >= N_NODES) return;
    float z[10]; float m = -1e30f;
    #pragma unroll
    for (int c = 0; c < 10; ++c) {
        z[c] = agg2[(size_t)n * 10 + c] + hr2[(size_t)n * 10 + c];
        m = fmaxf(m, z[c]);
    }
    float s = 0.f;
    #pragma unroll
    for (int c = 0; c < 10; ++c) s += expf(z[c] - m);
    float ls = logf(s);
    #pragma unroll
    for (int c = 0; c < 10; ++c) out[(size_t)n * 10 + c] = z[c] - m - ls;
}

// ---------------------------------------------------------------------------
extern "C" void kernel_launch(void* const* d_in, const int* in_sizes, int n_in,
                              void* d_out, int out_size, void* d_ws, size_t ws_size,
                              hipStream_t stream) {
    const float* x     = (const float*)d_in[0];
    const float* ea    = (const float*)d_in[1];
    const int*   eidx  = (const int*)d_in[2];
    const float* W1    = (const float*)d_in[3];
    const float* b1    = (const float*)d_in[4];
    const float* We1   = (const float*)d_in[5];
    const float* be1   = (const float*)d_in[6];
    const float* root1 = (const float*)d_in[7];
    const float* bias1 = (const float*)d_in[8];
    const float* We2   = (const float*)d_in[9];
    const float* be2   = (const float*)d_in[10];
    const float* root2 = (const float*)d_in[11];
    const float* bias2 = (const float*)d_in[12];
    float* out = (float*)d_out;

    // workspace layout (float units; all offsets 16B-aligned)
    float* ws = (float*)d_ws;
    ushort* h_bf = (ushort*)ws;                       // 1.28M ushort = 640000 f
    ushort* Bt   = (ushort*)(ws + 640000);            // 147456 ushort -> 73728 f pad
    ushort* G1   = (ushort*)(ws + 640000 + 73728);    // 10.24M ushort = 5120000 f
    float* hrb1 = ws + 640000 + 73728 + 5120000;      // 640000
    float* hb1  = hrb1 + 640000;                      // 640000
    float* agg1 = hb1  + 640000;                      // 640000
    float* h2   = agg1 + 640000;                      // 640000
    float* G2   = h2   + 640000;                      // 1600000
    float* hb2  = G2   + 1600000;                     // 100000
    float* hr2  = hb2  + 100000;                      // 100000
    float* agg2 = hr2  + 100000;                      // 100000

    hipMemsetAsync(agg1, 0, 640000 * sizeof(float), stream);
    hipMemsetAsync(agg2, 0, 100000 * sizeof(float), stream);

    k1_node_linear<<<1250, 256, 0, stream>>>(x, W1, b1, h_bf);
    k2_prep<<<576, 256, 0, stream>>>(We1, root1, be1, Bt);
    k3_mfma<<<dim3(157, 18), 256, 0, stream>>>(h_bf, Bt, bias1, G1, hrb1, hb1);
    k4_edge1<<<7500, 256, 0, stream>>>(ea, eidx, eidx + N_EDGES, G1, hb1, agg1);
    k5_h2<<<2500, 256, 0, stream>>>(agg1, hrb1, h2);
    k6_node_gemm2<<<704, 256, 0, stream>>>(h2, We2, be2, root2, bias2, G2, hb2, hr2);
    k7_edge2<<<118, 256, 0, stream>>>(ea, eidx, eidx + N_EDGES, G2, hb2, agg2);
    k8_logsoftmax<<<40, 256, 0, stream>>>(agg2, hr2, out);
}

// Round 3
// 162.995 us; speedup vs baseline: 1.3570x; 1.1426x over previous
//
#include <hip/hip_runtime.h>

#define N_NODES 10000
#define N_EDGES 30000
#define DIN     64
#define EDIM    16
#define H1      128
#define H2      64
#define C_OUT   10

typedef __bf16 bfrag __attribute__((ext_vector_type(8)));
typedef float  f32x4 __attribute__((ext_vector_type(4)));

__device__ __forceinline__ ushort f2bf(float f) {
    union { float f; unsigned u; } x; x.f = f;
    unsigned r = x.u + 0x7fffu + ((x.u >> 16) & 1u);   // RNE; inputs finite
    return (ushort)(r >> 16);
}
__device__ __forceinline__ float bf2f(ushort s) {
    union { unsigned u; float f; } x; x.u = ((unsigned)s) << 16;
    return x.f;
}

// ---------------------------------------------------------------------------
// kA: multi-role prep kernel (block-uniform branch):
//   blocks [0,1250):      h = relu(x@W1+b1) -> bf16
//   blocks [1250,1826):   pack B1t[1152][128] bf16 (We1 cols, root1, be1)
//   blocks [1826,1874):   pack B2t[192][64]  bf16 (We2 cols, be2, root2, pad 0)
//   blocks [1874,2055):   zero agg1||agg2 (740000 floats contiguous)
#define KA_B1   1250
#define KA_B2   (KA_B1 + 576)
#define KA_B3   (KA_B2 + 48)
#define KA_B4   (KA_B3 + 181)
__global__ __launch_bounds__(256) void kA_prep(
        const float* __restrict__ x, const float* __restrict__ W1,
        const float* __restrict__ b1,
        const float* __restrict__ We1, const float* __restrict__ root1,
        const float* __restrict__ be1,
        const float* __restrict__ We2, const float* __restrict__ be2,
        const float* __restrict__ root2,
        ushort* __restrict__ h_bf, ushort* __restrict__ B1t,
        ushort* __restrict__ B2t, float* __restrict__ aggz) {
    int t = threadIdx.x;
    int bx = blockIdx.x;
    if (bx < KA_B1) {
        // ---- h = relu(x @ W1 + b1), bf16 out ----
        __shared__ float w_lds[DIN * H1];
        __shared__ float b_lds[H1];
        __shared__ float x_lds[8][DIN];
        for (int idx = t; idx < DIN * H1 / 4; idx += 256)
            ((float4*)w_lds)[idx] = ((const float4*)W1)[idx];
        if (t < H1) b_lds[t] = b1[t];
        int n0 = bx * 8;
        if (t < 128) {
            int row = t >> 4, c4 = t & 15;
            int n = n0 + row;
            float4 v = make_float4(0.f, 0.f, 0.f, 0.f);
            if (n < N_NODES) v = ((const float4*)(x + (size_t)n * DIN))[c4];
            ((float4*)(x_lds[row]))[c4] = v;
        }
        __syncthreads();
        int nl = t >> 5;
        int o  = (t & 31) * 4;
        int n  = n0 + nl;
        float4 acc = *(const float4*)&b_lds[o];
        #pragma unroll 8
        for (int i = 0; i < DIN; ++i) {
            float xv = x_lds[nl][i];
            float4 w = *(const float4*)&w_lds[i * H1 + o];
            acc.x = fmaf(xv, w.x, acc.x);
            acc.y = fmaf(xv, w.y, acc.y);
            acc.z = fmaf(xv, w.z, acc.z);
            acc.w = fmaf(xv, w.w, acc.w);
        }
        if (n < N_NODES) {
            ushort4 s;
            s.x = f2bf(fmaxf(acc.x, 0.f));
            s.y = f2bf(fmaxf(acc.y, 0.f));
            s.z = f2bf(fmaxf(acc.z, 0.f));
            s.w = f2bf(fmaxf(acc.w, 0.f));
            *(ushort4*)&h_bf[(size_t)n * H1 + o] = s;
        }
    } else if (bx < KA_B2) {
        // ---- pack B1t: c in [0,1152), i in [0,128) ----
        int idx = (bx - KA_B1) * 256 + t;
        int c = idx >> 7, i = idx & 127;
        float v;
        if (c < 1024)      v = We1[(size_t)(c >> 6) * (H1 * H2) + i * 64 + (c & 63)];
        else if (c < 1088) v = root1[i * 64 + (c - 1024)];
        else               v = be1[i * 64 + (c - 1088)];
        B1t[idx] = f2bf(v);
    } else if (bx < KA_B3) {
        // ---- pack B2t: c in [0,192), j in [0,64) ----
        int idx = (bx - KA_B2) * 256 + t;
        int c = idx >> 6, j = idx & 63;
        float v = 0.f;
        if (c < 160)      v = We2[(size_t)(c / 10) * 640 + j * 10 + (c % 10)];
        else if (c < 170) v = be2[j * 10 + (c - 160)];
        else if (c < 180) v = root2[j * 10 + (c - 170)];
        B2t[idx] = f2bf(v);
    } else {
        // ---- zero agg1||agg2: 740000 floats = 185000 float4 ----
        int zb = bx - KA_B3;
        for (int i = zb * 256 + t; i < 185000; i += 181 * 256)
            ((float4*)aggz)[i] = make_float4(0.f, 0.f, 0.f, 0.f);
    }
}

// ---------------------------------------------------------------------------
// K3: bf16 MFMA GEMM  C[10000 x 1152] = h_bf[10000 x 128] @ B1[128 x 1152]
// grid.x = M-tiles of 128 (79), grid.y = col-blocks of 64 (18).
// wave = 32 rows x 64 cols (2 A-frags share each B-frag).
__global__ __launch_bounds__(256) void k3_mfma(
        const ushort* __restrict__ h_bf, const ushort* __restrict__ Bt,
        const float* __restrict__ bias1,
        ushort* __restrict__ G1, float* __restrict__ hrb1, float* __restrict__ hb1) {
    int t = threadIdx.x;
    int wave = t >> 6, lane = t & 63;
    int quad = lane >> 4, lrow = lane & 15;
    int y = blockIdx.y;
    int nbase = blockIdx.x * 128 + wave * 32;
    int ar0 = nbase + lrow;       if (ar0 > N_NODES - 1) ar0 = N_NODES - 1;
    int ar1 = nbase + 16 + lrow;  if (ar1 > N_NODES - 1) ar1 = N_NODES - 1;
    const ushort* bbase = Bt + (size_t)y * 64 * 128;
    f32x4 acc0[4] = {}, acc1[4] = {};
    #pragma unroll
    for (int kc = 0; kc < 128; kc += 32) {
        bfrag a0 = *reinterpret_cast<const bfrag*>(h_bf + (size_t)ar0 * 128 + kc + quad * 8);
        bfrag a1 = *reinterpret_cast<const bfrag*>(h_bf + (size_t)ar1 * 128 + kc + quad * 8);
        #pragma unroll
        for (int ct = 0; ct < 4; ++ct) {
            bfrag b = *reinterpret_cast<const bfrag*>(
                bbase + (size_t)(ct * 16 + lrow) * 128 + kc + quad * 8);
            acc0[ct] = __builtin_amdgcn_mfma_f32_16x16x32_bf16(a0, b, acc0[ct], 0, 0, 0);
            acc1[ct] = __builtin_amdgcn_mfma_f32_16x16x32_bf16(a1, b, acc1[ct], 0, 0, 0);
        }
    }
    #pragma unroll
    for (int half = 0; half < 2; ++half) {
        int rbase = nbase + half * 16 + quad * 4;
        #pragma unroll
        for (int ct = 0; ct < 4; ++ct) {
            int col = ct * 16 + lrow;
            f32x4 a = half ? acc1[ct] : acc0[ct];
            #pragma unroll
            for (int r = 0; r < 4; ++r) {
                int n = rbase + r;
                if (n >= N_NODES) continue;
                float v = a[r];
                if (y < 16) {
                    G1[(size_t)n * 1024 + y * 64 + col] = f2bf(v);
                } else if (y == 16) {
                    hrb1[(size_t)n * 64 + col] = v + bias1[col];
                } else {
                    hb1[(size_t)n * 64 + col] = v;
                }
            }
        }
    }
}

// ---------------------------------------------------------------------------
// K4: edge pass 1. wave per edge, lane = output o. G1 in bf16.
__global__ __launch_bounds__(256) void k4_edge1(
        const float* __restrict__ ea, const int* __restrict__ src_idx,
        const int* __restrict__ dst_idx, const ushort* __restrict__ G1,
        const float* __restrict__ hb1, float* __restrict__ agg1) {
    int t = threadIdx.x;
    int e = blockIdx.x * 4 + (t >> 6);
    int o = t & 63;
    int s = src_idx[e], d = dst_idx[e];
    float m = hb1[(size_t)s * 64 + o];
    const ushort* g = G1 + (size_t)s * 1024 + o;
    const float* a = ea + (size_t)e * 16;
    #pragma unroll
    for (int k = 0; k < 16; ++k) m = fmaf(a[k], bf2f(g[k * 64]), m);
    atomicAdd(&agg1[(size_t)d * 64 + o], m);
}

// ---------------------------------------------------------------------------
// K56: layer-2 node GEMM via MFMA, consuming relu(agg1+hrb1) inline.
//   C[10000 x 192] = relu(agg1+hrb1)[10000 x 64] @ B2[64 x 192]
// grid.x = M-tiles of 64 (157), grid.y = 3 col-blocks.
//   global col cg: <160 -> G2 f32; 160..169 -> hb2; 170..179 -> hr2(+bias2); else drop
__global__ __launch_bounds__(256) void k56_mfma(
        const float* __restrict__ agg1, const float* __restrict__ hrb1,
        const ushort* __restrict__ B2t, const float* __restrict__ bias2,
        float* __restrict__ G2, float* __restrict__ hb2, float* __restrict__ hr2) {
    int t = threadIdx.x;
    int wave = t >> 6, lane = t & 63;
    int quad = lane >> 4, lrow = lane & 15;
    int y = blockIdx.y;
    int n0 = blockIdx.x * 64 + wave * 16;
    int arow = n0 + lrow; if (arow > N_NODES - 1) arow = N_NODES - 1;
    f32x4 acc[4] = {};
    #pragma unroll
    for (int kc = 0; kc < 64; kc += 32) {
        size_t off = (size_t)arow * 64 + kc + quad * 8;
        f32x4 p0 = *(const f32x4*)(agg1 + off);
        f32x4 p1 = *(const f32x4*)(agg1 + off + 4);
        f32x4 q0 = *(const f32x4*)(hrb1 + off);
        f32x4 q1 = *(const f32x4*)(hrb1 + off + 4);
        bfrag a;
        #pragma unroll
        for (int j = 0; j < 4; ++j) {
            a[j]     = (__bf16)fmaxf(p0[j] + q0[j], 0.f);
            a[j + 4] = (__bf16)fmaxf(p1[j] + q1[j], 0.f);
        }
        #pragma unroll
        for (int ct = 0; ct < 4; ++ct) {
            bfrag b = *reinterpret_cast<const bfrag*>(
                B2t + (size_t)(y * 64 + ct * 16 + lrow) * 64 + kc + quad * 8);
            acc[ct] = __builtin_amdgcn_mfma_f32_16x16x32_bf16(a, b, acc[ct], 0, 0, 0);
        }
    }
    #pragma unroll
    for (int ct = 0; ct < 4; ++ct) {
        int cg = y * 64 + ct * 16 + lrow;
        #pragma unroll
        for (int r = 0; r < 4; ++r) {
            int n = n0 + quad * 4 + r;
            if (n >= N_NODES) continue;
            float v = acc[ct][r];
            if (cg < 160)      G2[(size_t)n * 160 + cg] = v;
            else if (cg < 170) hb2[(size_t)n * 10 + (cg - 160)] = v;
            else if (cg < 180) hr2[(size_t)n * 10 + (cg - 170)] = v + bias2[cg - 170];
        }
    }
}

// ---------------------------------------------------------------------------
// K7: edge pass 2. thread per edge.
__global__ void k7_edge2(const float* __restrict__ ea, const int* __restrict__ src_idx,
                         const int* __restrict__ dst_idx, const float* __restrict__ G2,
                         const float* __restrict__ hb2, float* __restrict__ agg2) {
    int e = blockIdx.x * blockDim.x + threadIdx.x;
    if (e >= N_EDGES) return;
    int s = src_idx[e], d = dst_idx[e];
    float msg[10];
    #pragma unroll
    for (int c = 0; c < 10; ++c) msg[c] = hb2[(size_t)s * 10 + c];
    const float* a = ea + (size_t)e * 16;
    const float* g = G2 + (size_t)s * 160;
    #pragma unroll
    for (int k = 0; k < 16; ++k) {
        float av = a[k];
        #pragma unroll
        for (int c = 0; c < 10; ++c) msg[c] = fmaf(av, g[k * 10 + c], msg[c]);
    }
    #pragma unroll
    for (int c = 0; c < 10; ++c) atomicAdd(&agg2[(size_t)d * 10 + c], msg[c]);
}

// ---------------------------------------------------------------------------
// K8: z = agg2 + hr2; out = log_softmax(z)
__global__ void k8_logsoftmax(const float* __restrict__ agg2, const float* __restrict__ hr2,
                              float* __restrict__ out) {
    int n = blockIdx.x * blockDim.x + threadIdx.x;
    if (n >= N_NODES) return;
    float z[10]; float m = -1e30f;
    #pragma unroll
    for (int c = 0; c < 10; ++c) {
        z[c] = agg2[(size_t)n * 10 + c] + hr2[(size_t)n * 10 + c];
        m = fmaxf(m, z[c]);
    }
    float s = 0.f;
    #pragma unroll
    for (int c = 0; c < 10; ++c) s += expf(z[c] - m);
    float ls = logf(s);
    #pragma unroll
    for (int c = 0; c < 10; ++c) out[(size_t)n * 10 + c] = z[c] - m - ls;
}

// ---------------------------------------------------------------------------
extern "C" void kernel_launch(void* const* d_in, const int* in_sizes, int n_in,
                              void* d_out, int out_size, void* d_ws, size_t ws_size,
                              hipStream_t stream) {
    const float* x     = (const float*)d_in[0];
    const float* ea    = (const float*)d_in[1];
    const int*   eidx  = (const int*)d_in[2];
    const float* W1    = (const float*)d_in[3];
    const float* b1    = (const float*)d_in[4];
    const float* We1   = (const float*)d_in[5];
    const float* be1   = (const float*)d_in[6];
    const float* root1 = (const float*)d_in[7];
    const float* bias1 = (const float*)d_in[8];
    const float* We2   = (const float*)d_in[9];
    const float* be2   = (const float*)d_in[10];
    const float* root2 = (const float*)d_in[11];
    const float* bias2 = (const float*)d_in[12];
    float* out = (float*)d_out;

    // workspace layout (float units, all 16B-aligned)
    float* ws = (float*)d_ws;
    ushort* h_bf = (ushort*)ws;                        // 1,280,000 us = 640,000 f
    ushort* B1t  = (ushort*)(ws + 640000);             // 147,456 us -> 73,728 f
    ushort* B2t  = (ushort*)(ws + 713728);             // 12,288 us -> 6,144 f
    ushort* G1   = (ushort*)(ws + 719872);             // 10,240,000 us -> 5,120,000 f
    float* hrb1 = ws + 719872 + 5120000;               // 640,000
    float* hb1  = hrb1 + 640000;                       // 640,000
    float* agg1 = hb1  + 640000;                       // 640,000  (contiguous with agg2)
    float* agg2 = agg1 + 640000;                       // 100,000
    float* G2   = agg2 + 100000;                       // 1,600,000
    float* hb2  = G2   + 1600000;                      // 100,000
    float* hr2  = hb2  + 100000;                       // 100,000

    kA_prep<<<KA_B4, 256, 0, stream>>>(x, W1, b1, We1, root1, be1, We2, be2, root2,
                                       h_bf, B1t, B2t, agg1);
    k3_mfma<<<dim3(79, 18), 256, 0, stream>>>(h_bf, B1t, bias1, G1, hrb1, hb1);
    k4_edge1<<<7500, 256, 0, stream>>>(ea, eidx, eidx + N_EDGES, G1, hb1, agg1);
    k56_mfma<<<dim3(157, 3), 256, 0, stream>>>(agg1, hrb1, B2t, bias2, G2, hb2, hr2);
    k7_edge2<<<118, 256, 0, stream>>>(ea, eidx, eidx + N_EDGES, G2, hb2, agg2);
    k8_logsoftmax<<<40, 256, 0, stream>>>(agg2, hr2, out);
}